// Round 5
// baseline (89.467 us; speedup 1.0000x reference)
//
#include <hip/hip_runtime.h>
#include <math.h>

// Match the numpy/JAX reference op-for-op: no FMA contraction anywhere in
// the expressions that feed discrete decisions (alpha values, voxel trunc).
#pragma clang fp contract(off)

static constexpr int HH = 200, WW = 200;
static constexpr int NRAY = HH * WW;        // 40000
static constexpr int WPT  = 8;              // windows per thread
static constexpr int NBATCH = 33;           // 33*8 = 264 >= max 258 windows

// ws layout (float index); per-ray arrays stride NRAY
static constexpr int WS_SDD0 = 0;
static constexpr int WS_SDD1 = 40000;
static constexpr int WS_SDD2 = 80000;
static constexpr int WS_AMIN = 120000;
static constexpr int WS_AMAX = 160000;
static constexpr int WS_NORM = 200000;
static constexpr int WS_KST  = 240000;      // int
static constexpr int WS_NK   = 280000;      // int, -1 = no intersection
static constexpr int WS_UNI  = 320000;      // src0..2, spn0..5
static constexpr size_t WS_BYTES = (WS_UNI + 8) * 4;

__device__ __forceinline__ float alpha_of(float k, float sp, float src, float sdd) {
    return (k * sp - src) / sdd;   // reference: (k*spacing - src)/sdd, mul-sub-div
}

// ---------------- pre-kernel: per-ray geometry + dominant-axis k-range --------
__global__ __launch_bounds__(256)
void drr_pre(const float* __restrict__ spacing,
             const float* __restrict__ sdrP,  const float* __restrict__ thetaP,
             const float* __restrict__ phiP,  const float* __restrict__ gammaP,
             const float* __restrict__ bxP,   const float* __restrict__ byP,
             const float* __restrict__ bzP,   float* __restrict__ ws)
{
    const int rid = blockIdx.x * blockDim.x + threadIdx.x;
    if (rid >= NRAY) return;
    const int it = rid % HH, is = rid / HH;

    const float sdr = sdrP[0];
    const float th = thetaP[0], ph = phiP[0], ga = gammaP[0];
    const float ct = cosf(th), st = sinf(th);
    const float cp = cosf(ph), sp = sinf(ph);
    const float cg = cosf(ga), sg = sinf(ga);

    const float rot[3][3] = {
        { ct*cp, ct*sp*sg - st*cg, ct*sp*cg + st*sg },
        { st*cp, st*sp*sg + ct*cg, st*sp*cg - ct*sg },
        { -sp,   cp*sg,            cp*cg            }
    };

    float u[3], v[3], source[3], trans[3], src[3], spn[3];
    trans[0] = bxP[0]; trans[1] = byP[0]; trans[2] = bzP[0];
    for (int a = 0; a < 3; ++a) {
        source[a] = sdr * rot[a][0];
        u[a] = (sdr * rot[a][1]) / sdr;
        v[a] = (sdr * rot[a][2]) / sdr;
        src[a] = source[a] + trans[a];
        spn[a] = spacing[a];
    }

    const float tc = (float)(it - HH/2 + 1) * 2.0f;   // DELX
    const float sc = (float)(is - WW/2 + 1) * 2.0f;   // DELY

    float sdd[3];
    float nrm2 = 0.0f;
    for (int a = 0; a < 3; ++a) {
        float tg = tc * u[a] + sc * v[a];
        tg = tg - source[a];
        tg = tg + trans[a];
        float dd = (tg - src[a]) + 1e-8f;
        sdd[a] = dd;
        nrm2 = nrm2 + dd * dd;
    }

    float amin = -INFINITY, amax = INFINITY;
    for (int a = 0; a < 3; ++a) {
        float a0 = (0.0f - src[a]) / sdd[a];
        float a1 = (256.0f * spn[a] - src[a]) / sdd[a];
        amin = fmaxf(amin, fminf(a0, a1));
        amax = fminf(amax, fmaxf(a0, a1));
    }

    ws[WS_SDD0 + rid] = sdd[0];
    ws[WS_SDD1 + rid] = sdd[1];
    ws[WS_SDD2 + rid] = sdd[2];
    ws[WS_AMIN + rid] = amin;
    ws[WS_AMAX + rid] = amax;
    ws[WS_NORM + rid] = sqrtf(nrm2);

    int* wsi = (int*)ws;
    if (amax > amin) {
        // dominant axis = most crossings = argmax |sdd|/spn
        const float r0 = fabsf(sdd[0]) / spn[0];
        const float r1 = fabsf(sdd[1]) / spn[1];
        const float r2 = fabsf(sdd[2]) / spn[2];
        int d = 0; float rb = r0;
        if (r1 > rb) { d = 1; rb = r1; }
        if (r2 > rb) { d = 2; }
        const float sd = (d==0) ? sdd[0] : ((d==1) ? sdd[1] : sdd[2]);
        const float sr = (d==0) ? src[0] : ((d==1) ? src[1] : src[2]);
        const float spv= (d==0) ? spn[0] : ((d==1) ? spn[1] : spn[2]);

        int kStart, nk;
        if (sd > 0.0f) {       // alpha increasing in k; crossings in order k = kA..kL
            float kf = (amin * sd + sr) / spv;
            int k = (int)floorf(kf); k = k < 0 ? 0 : (k > 257 ? 257 : k);
            while (k > 0    && alpha_of((float)(k-1), spv, sr, sd) >= amin) --k;
            while (k <= 256 && alpha_of((float)k,     spv, sr, sd) <  amin) ++k;
            const int kA = k;  // smallest k with alpha >= amin (257 = none)
            kf = (amax * sd + sr) / spv;
            k = (int)floorf(kf); k = k < -1 ? -1 : (k > 256 ? 256 : k);
            while (k < 256 && alpha_of((float)(k+1), spv, sr, sd) <= amax) ++k;
            while (k >= 0  && alpha_of((float)k,     spv, sr, sd) >  amax) --k;
            const int kL = k;  // largest k with alpha <= amax (-1 = none)
            nk = kL - kA + 1; if (nk < 0) nk = 0;
            kStart = kA;
        } else {               // alpha decreasing in k; crossings in order k = kB..kC (down)
            float kf = (amin * sd + sr) / spv;
            int k = (int)floorf(kf); k = k < -1 ? -1 : (k > 256 ? 256 : k);
            while (k < 256 && alpha_of((float)(k+1), spv, sr, sd) >= amin) ++k;
            while (k >= 0  && alpha_of((float)k,     spv, sr, sd) <  amin) --k;
            const int kB = k;  // largest k with alpha >= amin
            kf = (amax * sd + sr) / spv;
            k = (int)floorf(kf); k = k < 0 ? 0 : (k > 257 ? 257 : k);
            while (k > 0    && alpha_of((float)(k-1), spv, sr, sd) <= amax) --k;
            while (k <= 256 && alpha_of((float)k,     spv, sr, sd) >  amax) ++k;
            const int kC = k;  // smallest k with alpha <= amax
            nk = kB - kC + 1; if (nk < 0) nk = 0;
            kStart = kB;
        }
        wsi[WS_KST + rid] = kStart;
        wsi[WS_NK  + rid] = nk;
    } else {
        wsi[WS_KST + rid] = 0;
        wsi[WS_NK  + rid] = -1;   // no intersection: output stays 0
    }

    if (rid == 0) {
        ws[WS_UNI + 0] = src[0]; ws[WS_UNI + 1] = src[1]; ws[WS_UNI + 2] = src[2];
        ws[WS_UNI + 3] = spn[0]; ws[WS_UNI + 4] = spn[1]; ws[WS_UNI + 5] = spn[2];
    }
}

// ---------------- main: WPT dominant-axis windows per thread ------------------
#define ADV_E { je += de; ne = (je >= 0 && je <= 256) ? alpha_of((float)je, sp_e, sr_e, sd_e) : INFINITY; }
#define ADV_F { jf += df; nf = (jf >= 0 && jf <= 256) ? alpha_of((float)jf, sp_f, sr_f, sd_f) : INFINITY; }

__global__ __launch_bounds__(256)
void drr_win(const float* __restrict__ vol,
             const float* __restrict__ ws,
             float* __restrict__ out)
{
    const int rid = blockIdx.x * blockDim.x + threadIdx.x;
    if (rid >= NRAY) return;
    const int* __restrict__ wsi = (const int*)ws;
    const int nk = wsi[WS_NK + rid];
    const int w0 = blockIdx.y * WPT;          // first window index of this thread
    if (w0 > nk) return;                      // covers nk == -1

    const float sdd0 = ws[WS_SDD0 + rid];
    const float sdd1 = ws[WS_SDD1 + rid];
    const float sdd2 = ws[WS_SDD2 + rid];
    const float amin = ws[WS_AMIN + rid];
    const float amax = ws[WS_AMAX + rid];
    const float nrm  = ws[WS_NORM + rid];
    const int kStart = wsi[WS_KST + rid];
    const float src0 = ws[WS_UNI + 0], src1 = ws[WS_UNI + 1], src2 = ws[WS_UNI + 2];
    const float spn0 = ws[WS_UNI + 3], spn1 = ws[WS_UNI + 4], spn2 = ws[WS_UNI + 5];
    const bool unit = (spn0 == 1.0f) & (spn1 == 1.0f) & (spn2 == 1.0f);

    // dominant axis (identical ops to pre-kernel -> identical d)
    const float r0 = fabsf(sdd0) / spn0, r1 = fabsf(sdd1) / spn1, r2 = fabsf(sdd2) / spn2;
    int d = 0; float rb = r0;
    if (r1 > rb) { d = 1; rb = r1; }
    if (r2 > rb) { d = 2; }
    const int e = (d == 0) ? 1 : 0;           // e in {0,1}
    const int f = (d == 2) ? 1 : 2;           // f in {1,2}

    const float sd_d = (d==0) ? sdd0 : ((d==1) ? sdd1 : sdd2);
    const float sr_d = (d==0) ? src0 : ((d==1) ? src1 : src2);
    const float sp_d = (d==0) ? spn0 : ((d==1) ? spn1 : spn2);
    const float sd_e = (e==0) ? sdd0 : sdd1;
    const float sr_e = (e==0) ? src0 : src1;
    const float sp_e = (e==0) ? spn0 : spn1;
    const float sd_f = (f==1) ? sdd1 : sdd2;
    const float sr_f = (f==1) ? src1 : src2;
    const float sp_f = (f==1) ? spn1 : spn2;
    const int dir_d = (sd_d > 0.0f) ? 1 : -1;

    // 9 window boundaries, independent divides (ILP, no serial chain)
    float b[WPT + 1];
    #pragma unroll
    for (int i = 0; i <= WPT; ++i) {
        const int m = w0 + i;
        int km = kStart + dir_d * (m - 1);
        km = km < 0 ? 0 : (km > 256 ? 256 : km);
        const float av = alpha_of((float)km, sp_d, sr_d, sd_d);
        b[i] = (m == 0) ? amin : ((m <= nk) ? av : amax);
    }

    // minor-axis pointers: first crossing (traversal order) with alpha > b[0]
    const float LO = b[0];
    int je, de; float ne;
    {
        const float sd = sd_e, sr = sr_e, spv = sp_e;
        const bool pos = sd > 0.0f;
        de = pos ? 1 : -1;
        const float kf = (LO * sd + sr) / spv;
        int j;
        if (pos) {
            j = (int)floorf(kf) + 1; j = j < 0 ? 0 : (j > 257 ? 257 : j);
            while (j > 0    && alpha_of((float)(j-1), spv, sr, sd) >  LO) --j;
            while (j <= 256 && alpha_of((float)j,     spv, sr, sd) <= LO) ++j;
            ne = (j <= 256) ? alpha_of((float)j, spv, sr, sd) : INFINITY;
        } else {
            j = (int)ceilf(kf) - 1; j = j > 256 ? 256 : (j < -1 ? -1 : j);
            while (j < 256 && alpha_of((float)(j+1), spv, sr, sd) >  LO) ++j;
            while (j >= 0  && alpha_of((float)j,     spv, sr, sd) <= LO) --j;
            ne = (j >= 0) ? alpha_of((float)j, spv, sr, sd) : INFINITY;
        }
        je = j;
    }
    int jf, df; float nf;
    {
        const float sd = sd_f, sr = sr_f, spv = sp_f;
        const bool pos = sd > 0.0f;
        df = pos ? 1 : -1;
        const float kf = (LO * sd + sr) / spv;
        int j;
        if (pos) {
            j = (int)floorf(kf) + 1; j = j < 0 ? 0 : (j > 257 ? 257 : j);
            while (j > 0    && alpha_of((float)(j-1), spv, sr, sd) >  LO) --j;
            while (j <= 256 && alpha_of((float)j,     spv, sr, sd) <= LO) ++j;
            nf = (j <= 256) ? alpha_of((float)j, spv, sr, sd) : INFINITY;
        } else {
            j = (int)ceilf(kf) - 1; j = j > 256 ? 256 : (j < -1 ? -1 : j);
            while (j < 256 && alpha_of((float)(j+1), spv, sr, sd) >  LO) ++j;
            while (j >= 0  && alpha_of((float)j,     spv, sr, sd) <= LO) --j;
            nf = (j >= 0) ? alpha_of((float)j, spv, sr, sd) : INFINITY;
        }
        jf = j;
    }

    float acc = 0.0f;
    #pragma unroll
    for (int i = 0; i < WPT; ++i) {
        const int w = w0 + i;
        if (w > nk) break;
        const float lo = b[i], hi = b[i + 1];
        // consume crossings equal to a previous boundary (zero-width pieces = 0)
        while (ne <= lo) ADV_E;
        while (nf <= lo) ADV_F;
        float prev = lo;
        for (int g = 0; g < 64; ++g) {        // <= 1 interior crossing/axis typ.
            const float x = fminf(fminf(ne, nf), hi);
            const float step = x - prev;
            const float amid = 0.5f * (prev + x);

            // pts = src + amid * sdd  (reference order: mul then add — no FMA)
            const float p0 = src0 + amid * sdd0;
            const float p1 = src1 + amid * sdd1;
            const float p2 = src2 + amid * sdd2;
            float f0, f1v, f2v;
            if (unit) { f0 = p0; f1v = p1; f2v = p2; }
            else      { f0 = p0 / spn0; f1v = p1 / spn1; f2v = p2 / spn2; }
            f0  = fminf(fmaxf(f0 , 0.0f), 255.0f);
            f1v = fminf(fmaxf(f1v, 0.0f), 255.0f);
            f2v = fminf(fmaxf(f2v, 0.0f), 255.0f);
            const int i0 = (int)f0, i1 = (int)f1v, i2 = (int)f2v;

            // vol = volume[::-1] along axis 0; 255-i0 == 255^i0 for i0 in [0,255]
            const int addr = ((((255 ^ i0) << 8) + i1) << 8) + i2;
            acc = fmaf(step, vol[addr], acc);

            if (x >= hi) break;               // x == hi: window done
            const bool ae = (ne == x), af = (nf == x);
            if (ae) ADV_E;
            if (af) ADV_F;
            prev = x;
        }
    }

    const int it = rid % HH, is = rid / HH;
    atomicAdd(&out[it * WW + is], acc * nrm);
}

// ---------------- fallback (round-3 passing kernel, SPLIT=16) -----------------
#define MSPLIT 16
__global__ __launch_bounds__(256)
void drr_mono(const float* __restrict__ vol,
              const float* __restrict__ spacing,
              const float* __restrict__ sdrP,  const float* __restrict__ thetaP,
              const float* __restrict__ phiP,  const float* __restrict__ gammaP,
              const float* __restrict__ bxP,   const float* __restrict__ byP,
              const float* __restrict__ bzP,   float* __restrict__ out)
{
    const int tid = blockIdx.x * blockDim.x + threadIdx.x;
    if (tid >= NRAY * MSPLIT) return;
    const int seg = tid / NRAY;
    const int rid = tid - seg * NRAY;
    const int it  = rid % HH;
    const int is  = rid / HH;

    const float sdr = sdrP[0];
    const float th = thetaP[0], ph = phiP[0], ga = gammaP[0];
    const float ct = cosf(th), st = sinf(th);
    const float cp = cosf(ph), sp = sinf(ph);
    const float cg = cosf(ga), sg = sinf(ga);
    const float rot[3][3] = {
        { ct*cp, ct*sp*sg - st*cg, ct*sp*cg + st*sg },
        { st*cp, st*sp*sg + ct*cg, st*sp*cg - ct*sg },
        { -sp,   cp*sg,            cp*cg            }
    };
    float u[3], v[3], source[3], trans[3], src[3], spn[3];
    trans[0] = bxP[0]; trans[1] = byP[0]; trans[2] = bzP[0];
    for (int a = 0; a < 3; ++a) {
        source[a] = sdr * rot[a][0];
        u[a] = (sdr * rot[a][1]) / sdr;
        v[a] = (sdr * rot[a][2]) / sdr;
        src[a] = source[a] + trans[a];
        spn[a] = spacing[a];
    }
    const float tc = (float)(it - HH/2 + 1) * 2.0f;
    const float sc = (float)(is - WW/2 + 1) * 2.0f;
    float sdd[3]; float nrm2 = 0.0f;
    for (int a = 0; a < 3; ++a) {
        float tg = tc * u[a] + sc * v[a];
        tg = tg - source[a];
        tg = tg + trans[a];
        float dd = (tg - src[a]) + 1e-8f;
        sdd[a] = dd;
        nrm2 = nrm2 + dd * dd;
    }
    const bool unit = (spn[0] == 1.0f) & (spn[1] == 1.0f) & (spn[2] == 1.0f);
    float amin = -INFINITY, amax = INFINITY;
    for (int a = 0; a < 3; ++a) {
        float a0 = (0.0f - src[a]) / sdd[a];
        float a1 = (256.0f * spn[a] - src[a]) / sdd[a];
        amin = fmaxf(amin, fminf(a0, a1));
        amax = fminf(amax, fmaxf(a0, a1));
    }
    float acc = 0.0f;
    if (amax > amin) {
        const float blo = (seg == 0) ? amin
                        : amin + (amax - amin) * ((float)seg / (float)MSPLIT);
        const float bhi = (seg == MSPLIT - 1) ? amax
                        : amin + (amax - amin) * ((float)(seg + 1) / (float)MSPLIT);
        float kf[3], kst[3], nexta[3];
        float prev = -INFINITY;
        for (int a = 0; a < 3; ++a) {
            const float sd = sdd[a], sr = src[a], spv = spn[a];
            const bool pos = sd > 0.0f;
            kst[a] = pos ? 1.0f : -1.0f;
            const float kseed = (blo * sd + sr) / spv;
            int kk;
            if (pos) {
                kk = (int)floorf(kseed) + 1;
                kk = kk < 0 ? 0 : (kk > 257 ? 257 : kk);
                while (kk > 0    && alpha_of((float)(kk-1), spv, sr, sd) >  blo) --kk;
                while (kk <= 256 && alpha_of((float)kk,     spv, sr, sd) <= blo) ++kk;
                if (kk - 1 >= 0) {
                    float ap = alpha_of((float)(kk-1), spv, sr, sd);
                    if (ap >= amin && ap > prev) prev = ap;
                }
                nexta[a] = (kk <= 256) ? alpha_of((float)kk, spv, sr, sd) : INFINITY;
            } else {
                kk = (int)ceilf(kseed) - 1;
                kk = kk > 256 ? 256 : (kk < -1 ? -1 : kk);
                while (kk < 256 && alpha_of((float)(kk+1), spv, sr, sd) >  blo) ++kk;
                while (kk >= 0  && alpha_of((float)kk,     spv, sr, sd) <= blo) --kk;
                if (kk + 1 <= 256) {
                    float ap = alpha_of((float)(kk+1), spv, sr, sd);
                    if (ap >= amin && ap > prev) prev = ap;
                }
                nexta[a] = (kk >= 0) ? alpha_of((float)kk, spv, sr, sd) : INFINITY;
            }
            kf[a] = (float)kk;
        }
        for (int guard = 0; guard < 1024; ++guard) {
            const float q = fminf(fminf(nexta[0], nexta[1]), nexta[2]);
            if (!(q <= bhi)) break;
            const float step = q - prev;
            const float amid = 0.5f * (prev + q);
            const float p0 = src[0] + amid * sdd[0];
            const float p1 = src[1] + amid * sdd[1];
            const float p2 = src[2] + amid * sdd[2];
            float f0, f1, f2;
            if (unit) { f0 = p0; f1 = p1; f2 = p2; }
            else      { f0 = p0 / spn[0]; f1 = p1 / spn[1]; f2 = p2 / spn[2]; }
            f0 = fminf(fmaxf(f0, 0.0f), 255.0f);
            f1 = fminf(fmaxf(f1, 0.0f), 255.0f);
            f2 = fminf(fmaxf(f2, 0.0f), 255.0f);
            const int i0 = (int)f0, i1 = (int)f1, i2 = (int)f2;
            const int addr = ((((255 ^ i0) << 8) + i1) << 8) + i2;
            acc = fmaf(step, vol[addr], acc);
            prev = q;
            #pragma unroll
            for (int a = 0; a < 3; ++a) {
                if (nexta[a] == q) {
                    const float nkf = kf[a] + kst[a];
                    kf[a] = nkf;
                    const float al = alpha_of(nkf, spn[a], src[a], sdd[a]);
                    nexta[a] = (nkf >= 0.0f && nkf <= 256.0f) ? al : INFINITY;
                }
            }
        }
    }
    atomicAdd(&out[it * WW + is], acc * sqrtf(nrm2));
}

extern "C" void kernel_launch(void* const* d_in, const int* in_sizes, int n_in,
                              void* d_out, int out_size, void* d_ws, size_t ws_size,
                              hipStream_t stream)
{
    const float* vol     = (const float*)d_in[0];
    const float* spacing = (const float*)d_in[1];
    const float* sdr     = (const float*)d_in[2];
    const float* theta   = (const float*)d_in[3];
    const float* phi     = (const float*)d_in[4];
    const float* gamma   = (const float*)d_in[5];
    const float* bx      = (const float*)d_in[6];
    const float* by      = (const float*)d_in[7];
    const float* bz      = (const float*)d_in[8];
    float* out = (float*)d_out;

    // re-zero output every replay (graph captures this node): atomics accumulate.
    hipMemsetAsync(out, 0, (size_t)out_size * sizeof(float), stream);

    if (ws_size >= WS_BYTES) {
        float* ws = (float*)d_ws;
        const int rblocks = (NRAY + 255) / 256;      // 157
        drr_pre<<<rblocks, 256, 0, stream>>>(spacing, sdr, theta, phi, gamma,
                                             bx, by, bz, ws);
        drr_win<<<dim3(rblocks, NBATCH), 256, 0, stream>>>(vol, ws, out);
    } else {
        const int threads = NRAY * MSPLIT;           // 640000 = 2500 * 256
        drr_mono<<<threads / 256, 256, 0, stream>>>(vol, spacing, sdr, theta, phi,
                                                    gamma, bx, by, bz, out);
    }
}

// Round 6
// 59.247 us; speedup vs baseline: 1.5101x; 1.5101x over previous
//
#include <hip/hip_runtime.h>
#include <math.h>

// Match the numpy/JAX reference op-for-op: no FMA contraction anywhere in
// the expressions that feed discrete decisions (alpha values, voxel trunc).
#pragma clang fp contract(off)

#define SPLIT 16
static constexpr int HH = 200, WW = 200;
static constexpr int NRAY = HH * WW;

__device__ __forceinline__ float alpha_of(float k, float sp, float src, float sdd) {
    return (k * sp - src) / sdd;   // reference: (k*spacing - src)/sdd, mul-sub-div
}

// Merge loop specialized on unit spacing (k*1.0f == k exactly -> identical bits,
// saves the sp select+mul in the single-divide advance).
template<bool UNIT>
__device__ __forceinline__ float merge_loop(
    const float* __restrict__ vol, float bhi, float prev,
    float kf0, float kf1, float kf2,
    float kst0, float kst1, float kst2,
    float na0, float na1, float na2,
    float src0, float src1, float src2,
    float spn0, float spn1, float spn2,
    float sdd0, float sdd1, float sdd2)
{
    float acc = 0.0f;
    for (int g = 0; g < 1024; ++g) {
        const float q = fminf(fminf(na0, na1), na2);   // v_min3
        if (!(q <= bhi)) break;

        const float step = q - prev;
        const float amid = 0.5f * (prev + q);

        // pts = src + amid * sdd  (reference order: mul then add — no FMA)
        const float p0 = src0 + amid * sdd0;
        const float p1 = src1 + amid * sdd1;
        const float p2 = src2 + amid * sdd2;
        // idx = trunc(pts / spacing), clip [0,255]. p/1.0 == p exactly.
        float f0, f1, f2;
        if (UNIT) { f0 = p0; f1 = p1; f2 = p2; }
        else      { f0 = p0 / spn0; f1 = p1 / spn1; f2 = p2 / spn2; }
        f0 = fminf(fmaxf(f0, 0.0f), 255.0f);           // v_med3
        f1 = fminf(fmaxf(f1, 0.0f), 255.0f);
        f2 = fminf(fmaxf(f2, 0.0f), 255.0f);
        const int i0 = (int)f0, i1 = (int)f1, i2 = (int)f2;

        // vol = volume[::-1] along axis 0; 255-i0 == 255^i0 for i0 in [0,255]
        const int addr = ((((255 ^ i0) << 8) + i1) << 8) + i2;
        acc = fmaf(step, vol[addr], acc);
        prev = q;

        // Single-divide advance: exactly one axis consumes its crossing.
        // (Exact ties produce a zero-width interval next iteration -> adds 0.0,
        // bit-equivalent to the reference's duplicate-alpha handling.)
        const bool m0 = (na0 == q);
        const bool m1 = !m0 && (na1 == q);
        const float kf_s  = m0 ? kf0  : (m1 ? kf1  : kf2);
        const float kst_s = m0 ? kst0 : (m1 ? kst1 : kst2);
        const float sr_s  = m0 ? src0 : (m1 ? src1 : src2);
        const float sd_s  = m0 ? sdd0 : (m1 ? sdd1 : sdd2);
        const float nk = kf_s + kst_s;
        float al;
        if (UNIT) {
            al = (nk - sr_s) / sd_s;                   // == (nk*1.0f - sr)/sd
        } else {
            const float sp_s = m0 ? spn0 : (m1 ? spn1 : spn2);
            al = (nk * sp_s - sr_s) / sd_s;
        }
        const float nv = (nk >= 0.0f && nk <= 256.0f) ? al : INFINITY;
        if (m0)      { kf0 = nk; na0 = nv; }
        else if (m1) { kf1 = nk; na1 = nv; }
        else         { kf2 = nk; na2 = nv; }
    }
    return acc;
}

__global__ __launch_bounds__(256)
void drr_kernel(const float* __restrict__ vol,
                const float* __restrict__ spacing,
                const float* __restrict__ sdrP,
                const float* __restrict__ thetaP,
                const float* __restrict__ phiP,
                const float* __restrict__ gammaP,
                const float* __restrict__ bxP,
                const float* __restrict__ byP,
                const float* __restrict__ bzP,
                float* __restrict__ out)
{
    const int tid = blockIdx.x * blockDim.x + threadIdx.x;
    if (tid >= NRAY * SPLIT) return;
    const int seg = tid / NRAY;               // segment in high bits
    const int rid = tid - seg * NRAY;         // lanes = consecutive rid
    const int it  = rid % HH;                 // it fastest across lanes -> coalesced i2
    const int is  = rid / HH;

    const float sdr = sdrP[0];
    const float th = thetaP[0], ph = phiP[0], ga = gammaP[0];
    const float ct = cosf(th), st = sinf(th);
    const float cp = cosf(ph), sp = sinf(ph);
    const float cg = cosf(ga), sg = sinf(ga);

    // rotation = Rz @ Ry @ Rx
    const float rot[3][3] = {
        { ct*cp, ct*sp*sg - st*cg, ct*sp*cg + st*sg },
        { st*cp, st*sp*sg + ct*cg, st*sp*cg - ct*sg },
        { -sp,   cp*sg,            cp*cg            }
    };

    float u[3], v[3], source[3], trans[3], src[3], spn[3];
    trans[0] = bxP[0]; trans[1] = byP[0]; trans[2] = bzP[0];
    for (int a = 0; a < 3; ++a) {
        source[a] = sdr * rot[a][0];
        u[a] = (sdr * rot[a][1]) / sdr;
        v[a] = (sdr * rot[a][2]) / sdr;
        src[a] = source[a] + trans[a];
        spn[a] = spacing[a];
    }

    const float tc = (float)(it - HH/2 + 1) * 2.0f;   // DELX
    const float sc = (float)(is - WW/2 + 1) * 2.0f;   // DELY

    float sdd[3];
    float nrm2 = 0.0f;
    for (int a = 0; a < 3; ++a) {
        float tg = tc * u[a] + sc * v[a];
        tg = tg - source[a];     // + center
        tg = tg + trans[a];
        float dd = (tg - src[a]) + 1e-8f;  // sdd = tgt - src + EPS
        sdd[a] = dd;
        nrm2 = nrm2 + dd * dd;
    }
    const bool unit = (spn[0] == 1.0f) & (spn[1] == 1.0f) & (spn[2] == 1.0f);

    float amin = -INFINITY, amax = INFINITY;
    for (int a = 0; a < 3; ++a) {
        float a0 = (0.0f - src[a]) / sdd[a];
        float a1 = (256.0f * spn[a] - src[a]) / sdd[a];
        amin = fmaxf(amin, fminf(a0, a1));
        amax = fminf(amax, fmaxf(a0, a1));
    }

    float acc = 0.0f;
    if (amax > amin) {
        // Segment window (blo, bhi]; identical boundary arithmetic in all segs
        // of a ray, so the windows partition (amin, amax] exactly.
        const float blo = (seg == 0) ? amin
                        : amin + (amax - amin) * ((float)seg / (float)SPLIT);
        const float bhi = (seg == SPLIT - 1) ? amax
                        : amin + (amax - amin) * ((float)(seg + 1) / (float)SPLIT);

        float kf[3], kst[3], nexta[3];
        float prev = -INFINITY;   // largest in-range alpha <= blo

        for (int a = 0; a < 3; ++a) {
            const float sd = sdd[a], sr = src[a], spv = spn[a];
            const bool pos = sd > 0.0f;
            kst[a] = pos ? 1.0f : -1.0f;
            const float kseed = (blo * sd + sr) / spv;   // analytic seed
            int kk;
            if (pos) {   // alpha increases with k; pointer = smallest k with alpha(k) > blo
                kk = (int)floorf(kseed) + 1;
                kk = kk < 0 ? 0 : (kk > 257 ? 257 : kk);
                while (kk > 0    && alpha_of((float)(kk-1), spv, sr, sd) >  blo) --kk;
                while (kk <= 256 && alpha_of((float)kk,     spv, sr, sd) <= blo) ++kk;
                if (kk - 1 >= 0) {
                    float ap = alpha_of((float)(kk-1), spv, sr, sd);
                    if (ap >= amin && ap > prev) prev = ap;
                }
                nexta[a] = (kk <= 256) ? alpha_of((float)kk, spv, sr, sd) : INFINITY;
            } else {     // alpha increases as k decreases; pointer = largest k with alpha(k) > blo
                kk = (int)ceilf(kseed) - 1;
                kk = kk > 256 ? 256 : (kk < -1 ? -1 : kk);
                while (kk < 256 && alpha_of((float)(kk+1), spv, sr, sd) >  blo) ++kk;
                while (kk >= 0  && alpha_of((float)kk,     spv, sr, sd) <= blo) --kk;
                if (kk + 1 <= 256) {
                    float ap = alpha_of((float)(kk+1), spv, sr, sd);
                    if (ap >= amin && ap > prev) prev = ap;
                }
                nexta[a] = (kk >= 0) ? alpha_of((float)kk, spv, sr, sd) : INFINITY;
            }
            kf[a] = (float)kk;
        }

        if (unit) {
            acc = merge_loop<true >(vol, bhi, prev,
                                    kf[0], kf[1], kf[2], kst[0], kst[1], kst[2],
                                    nexta[0], nexta[1], nexta[2],
                                    src[0], src[1], src[2],
                                    spn[0], spn[1], spn[2],
                                    sdd[0], sdd[1], sdd[2]);
        } else {
            acc = merge_loop<false>(vol, bhi, prev,
                                    kf[0], kf[1], kf[2], kst[0], kst[1], kst[2],
                                    nexta[0], nexta[1], nexta[2],
                                    src[0], src[1], src[2],
                                    spn[0], spn[1], spn[2],
                                    sdd[0], sdd[1], sdd[2]);
        }
    }

    atomicAdd(&out[it * WW + is], acc * sqrtf(nrm2));
}

extern "C" void kernel_launch(void* const* d_in, const int* in_sizes, int n_in,
                              void* d_out, int out_size, void* d_ws, size_t ws_size,
                              hipStream_t stream)
{
    const float* vol     = (const float*)d_in[0];
    const float* spacing = (const float*)d_in[1];
    const float* sdr     = (const float*)d_in[2];
    const float* theta   = (const float*)d_in[3];
    const float* phi     = (const float*)d_in[4];
    const float* gamma   = (const float*)d_in[5];
    const float* bx      = (const float*)d_in[6];
    const float* by      = (const float*)d_in[7];
    const float* bz      = (const float*)d_in[8];
    float* out = (float*)d_out;

    // re-zero the output every replay (graph captures this memset node);
    // required because partial sums are atomically accumulated.
    hipMemsetAsync(out, 0, (size_t)out_size * sizeof(float), stream);

    const int threads = NRAY * SPLIT;   // 640000 = 2500 * 256 exactly
    const int block   = 256;
    const int grid    = threads / block;
    drr_kernel<<<grid, block, 0, stream>>>(vol, spacing, sdr, theta, phi, gamma,
                                           bx, by, bz, out);
}

// Round 7
// 58.717 us; speedup vs baseline: 1.5237x; 1.0090x over previous
//
#include <hip/hip_runtime.h>
#include <math.h>

// Match the numpy/JAX reference op-for-op: no FMA contraction anywhere in
// the expressions that feed discrete decisions (alpha values, voxel trunc).
#pragma clang fp contract(off)

#define SPLIT 13
static constexpr int HH = 200, WW = 200;
static constexpr int NRAY = HH * WW;

__device__ __forceinline__ float alpha_of(float k, float sp, float src, float sdd) {
    return (k * sp - src) / sdd;   // reference: (k*spacing - src)/sdd, mul-sub-div
}

// Merge loop with depth-2 alpha prefetch per axis: the head advance is a
// select (A0 <- A1), and the refill divide for A1 is issued the same
// iteration but consumed >= 1 iteration later -> divide off the recurrence.
// All alphas still come from the verbatim reference divide (bit-identical).
template<bool UNIT>
__device__ __forceinline__ float merge_loop(
    const float* __restrict__ vol, float bhi, float prev,
    float kf0, float kf1, float kf2,
    float kst0, float kst1, float kst2,
    float a00, float a01, float a02,     // A0: next crossing per axis
    float a10, float a11, float a12,     // A1: next-next crossing per axis
    float src0, float src1, float src2,
    float spn0, float spn1, float spn2,
    float sdd0, float sdd1, float sdd2)
{
    float acc = 0.0f;
    for (int g = 0; g < 1024; ++g) {
        const float q = fminf(fminf(a00, a01), a02);   // v_min3
        if (!(q <= bhi)) break;

        const float step = q - prev;
        const float amid = 0.5f * (prev + q);

        // pts = src + amid * sdd  (reference order: mul then add — no FMA)
        const float p0 = src0 + amid * sdd0;
        const float p1 = src1 + amid * sdd1;
        const float p2 = src2 + amid * sdd2;
        // idx = trunc(pts / spacing), clip [0,255]. p/1.0 == p exactly.
        float f0, f1, f2;
        if (UNIT) { f0 = p0; f1 = p1; f2 = p2; }
        else      { f0 = p0 / spn0; f1 = p1 / spn1; f2 = p2 / spn2; }
        f0 = fminf(fmaxf(f0, 0.0f), 255.0f);           // v_med3
        f1 = fminf(fmaxf(f1, 0.0f), 255.0f);
        f2 = fminf(fmaxf(f2, 0.0f), 255.0f);
        const int i0 = (int)f0, i1 = (int)f1, i2 = (int)f2;

        // vol = volume[::-1] along axis 0; 255-i0 == 255^i0 for i0 in [0,255]
        const int addr = ((((255 ^ i0) << 8) + i1) << 8) + i2;
        acc = fmaf(step, vol[addr], acc);
        prev = q;

        // Exactly one axis consumes its crossing (exact ties -> zero-width
        // interval next iteration, contributing exactly 0.0 — reference-equal).
        const bool m0 = (a00 == q);
        const bool m1 = !m0 && (a01 == q);
        const bool m2 = !m0 && !m1;

        // Single refill divide for the advanced axis (off the critical chain).
        const float kf_s  = m0 ? kf0  : (m1 ? kf1  : kf2);
        const float kst_s = m0 ? kst0 : (m1 ? kst1 : kst2);
        const float sr_s  = m0 ? src0 : (m1 ? src1 : src2);
        const float sd_s  = m0 ? sdd0 : (m1 ? sdd1 : sdd2);
        const float nk  = kf_s + kst_s;    // advanced axis's new pointer (= A1's k)
        const float nk2 = nk + kst_s;      // k for the refilled A1
        float al;
        if (UNIT) {
            al = (nk2 - sr_s) / sd_s;      // == (nk2*1.0f - sr)/sd, exact
        } else {
            const float sp_s = m0 ? spn0 : (m1 ? spn1 : spn2);
            al = (nk2 * sp_s - sr_s) / sd_s;
        }
        const float nv = (nk2 >= 0.0f && nk2 <= 256.0f) ? al : INFINITY;

        if (m0) { kf0 = nk; a00 = a10; a10 = nv; }
        if (m1) { kf1 = nk; a01 = a11; a11 = nv; }
        if (m2) { kf2 = nk; a02 = a12; a12 = nv; }
    }
    return acc;
}

__global__ __launch_bounds__(256)
void drr_kernel(const float* __restrict__ vol,
                const float* __restrict__ spacing,
                const float* __restrict__ sdrP,
                const float* __restrict__ thetaP,
                const float* __restrict__ phiP,
                const float* __restrict__ gammaP,
                const float* __restrict__ bxP,
                const float* __restrict__ byP,
                const float* __restrict__ bzP,
                float* __restrict__ out)
{
    const int tid = blockIdx.x * blockDim.x + threadIdx.x;
    if (tid >= NRAY * SPLIT) return;          // pad threads exit
    const int seg = tid / NRAY;               // segment in high bits
    const int rid = tid - seg * NRAY;         // lanes = consecutive rid
    const int it  = rid % HH;                 // it fastest across lanes -> coalesced i2
    const int is  = rid / HH;

    const float sdr = sdrP[0];
    const float th = thetaP[0], ph = phiP[0], ga = gammaP[0];
    const float ct = cosf(th), st = sinf(th);
    const float cp = cosf(ph), sp = sinf(ph);
    const float cg = cosf(ga), sg = sinf(ga);

    // rotation = Rz @ Ry @ Rx
    const float rot[3][3] = {
        { ct*cp, ct*sp*sg - st*cg, ct*sp*cg + st*sg },
        { st*cp, st*sp*sg + ct*cg, st*sp*cg - ct*sg },
        { -sp,   cp*sg,            cp*cg            }
    };

    float u[3], v[3], source[3], trans[3], src[3], spn[3];
    trans[0] = bxP[0]; trans[1] = byP[0]; trans[2] = bzP[0];
    for (int a = 0; a < 3; ++a) {
        source[a] = sdr * rot[a][0];
        u[a] = (sdr * rot[a][1]) / sdr;
        v[a] = (sdr * rot[a][2]) / sdr;
        src[a] = source[a] + trans[a];
        spn[a] = spacing[a];
    }

    const float tc = (float)(it - HH/2 + 1) * 2.0f;   // DELX
    const float sc = (float)(is - WW/2 + 1) * 2.0f;   // DELY

    float sdd[3];
    float nrm2 = 0.0f;
    for (int a = 0; a < 3; ++a) {
        float tg = tc * u[a] + sc * v[a];
        tg = tg - source[a];     // + center
        tg = tg + trans[a];
        float dd = (tg - src[a]) + 1e-8f;  // sdd = tgt - src + EPS
        sdd[a] = dd;
        nrm2 = nrm2 + dd * dd;
    }
    const bool unit = (spn[0] == 1.0f) & (spn[1] == 1.0f) & (spn[2] == 1.0f);

    float amin = -INFINITY, amax = INFINITY;
    for (int a = 0; a < 3; ++a) {
        float a0 = (0.0f - src[a]) / sdd[a];
        float a1 = (256.0f * spn[a] - src[a]) / sdd[a];
        amin = fmaxf(amin, fminf(a0, a1));
        amax = fminf(amax, fmaxf(a0, a1));
    }

    float acc = 0.0f;
    if (amax > amin) {
        // Segment window (blo, bhi]; identical boundary arithmetic in all segs
        // of a ray, so the windows partition (amin, amax] exactly.
        const float blo = (seg == 0) ? amin
                        : amin + (amax - amin) * ((float)seg / (float)SPLIT);
        const float bhi = (seg == SPLIT - 1) ? amax
                        : amin + (amax - amin) * ((float)(seg + 1) / (float)SPLIT);

        float kf[3], kst[3], a0h[3], a1h[3];
        float prev = -INFINITY;   // largest in-range alpha <= blo

        for (int a = 0; a < 3; ++a) {
            const float sd = sdd[a], sr = src[a], spv = spn[a];
            const bool pos = sd > 0.0f;
            kst[a] = pos ? 1.0f : -1.0f;
            const float kseed = (blo * sd + sr) / spv;   // analytic seed
            int kk;
            if (pos) {   // alpha increases with k; pointer = smallest k with alpha(k) > blo
                kk = (int)floorf(kseed) + 1;
                kk = kk < 0 ? 0 : (kk > 257 ? 257 : kk);
                while (kk > 0    && alpha_of((float)(kk-1), spv, sr, sd) >  blo) --kk;
                while (kk <= 256 && alpha_of((float)kk,     spv, sr, sd) <= blo) ++kk;
                if (kk - 1 >= 0) {
                    float ap = alpha_of((float)(kk-1), spv, sr, sd);
                    if (ap >= amin && ap > prev) prev = ap;
                }
                a0h[a] = (kk <= 256) ? alpha_of((float)kk, spv, sr, sd) : INFINITY;
            } else {     // alpha increases as k decreases; pointer = largest k with alpha(k) > blo
                kk = (int)ceilf(kseed) - 1;
                kk = kk > 256 ? 256 : (kk < -1 ? -1 : kk);
                while (kk < 256 && alpha_of((float)(kk+1), spv, sr, sd) >  blo) ++kk;
                while (kk >= 0  && alpha_of((float)kk,     spv, sr, sd) <= blo) --kk;
                if (kk + 1 <= 256) {
                    float ap = alpha_of((float)(kk+1), spv, sr, sd);
                    if (ap >= amin && ap > prev) prev = ap;
                }
                a0h[a] = (kk >= 0) ? alpha_of((float)kk, spv, sr, sd) : INFINITY;
            }
            kf[a] = (float)kk;
            const float nk1 = kf[a] + kst[a];            // prefetch depth 2
            a1h[a] = (nk1 >= 0.0f && nk1 <= 256.0f)
                   ? alpha_of(nk1, spv, sr, sd) : INFINITY;
        }

        if (unit) {
            acc = merge_loop<true >(vol, bhi, prev,
                                    kf[0], kf[1], kf[2], kst[0], kst[1], kst[2],
                                    a0h[0], a0h[1], a0h[2], a1h[0], a1h[1], a1h[2],
                                    src[0], src[1], src[2],
                                    spn[0], spn[1], spn[2],
                                    sdd[0], sdd[1], sdd[2]);
        } else {
            acc = merge_loop<false>(vol, bhi, prev,
                                    kf[0], kf[1], kf[2], kst[0], kst[1], kst[2],
                                    a0h[0], a0h[1], a0h[2], a1h[0], a1h[1], a1h[2],
                                    src[0], src[1], src[2],
                                    spn[0], spn[1], spn[2],
                                    sdd[0], sdd[1], sdd[2]);
        }
    }

    atomicAdd(&out[it * WW + is], acc * sqrtf(nrm2));
}

extern "C" void kernel_launch(void* const* d_in, const int* in_sizes, int n_in,
                              void* d_out, int out_size, void* d_ws, size_t ws_size,
                              hipStream_t stream)
{
    const float* vol     = (const float*)d_in[0];
    const float* spacing = (const float*)d_in[1];
    const float* sdr     = (const float*)d_in[2];
    const float* theta   = (const float*)d_in[3];
    const float* phi     = (const float*)d_in[4];
    const float* gamma   = (const float*)d_in[5];
    const float* bx      = (const float*)d_in[6];
    const float* by      = (const float*)d_in[7];
    const float* bz      = (const float*)d_in[8];
    float* out = (float*)d_out;

    // re-zero the output every replay (graph captures this memset node);
    // required because partial sums are atomically accumulated.
    hipMemsetAsync(out, 0, (size_t)out_size * sizeof(float), stream);

    // SPLIT=13: 520000 threads = 2032 blocks ~= 7.94 blocks/CU -> one clean
    // residency round (32 waves/CU at VGPR<=64) instead of 1.22 ragged rounds.
    const int threads = NRAY * SPLIT;
    const int block   = 256;
    const int grid    = (threads + block - 1) / block;   // 2032
    drr_kernel<<<grid, block, 0, stream>>>(vol, spacing, sdr, theta, phi, gamma,
                                           bx, by, bz, out);
}

// Round 8
// 57.244 us; speedup vs baseline: 1.5629x; 1.0257x over previous
//
#include <hip/hip_runtime.h>
#include <math.h>

// Keep non-contracted float math in all expressions that feed discrete
// decisions (alpha seeds, voxel trunc) — matches numpy/JAX op-for-op.
#pragma clang fp contract(off)

#define SPLIT 13
static constexpr int HH = 200, WW = 200;
static constexpr int NRAY = HH * WW;

__device__ __forceinline__ float alpha_of(float k, float sp, float src, float sdd) {
    return (k * sp - src) / sdd;   // reference: (k*spacing - src)/sdd, mul-sub-div
}

// Traversal pointer at threshold X: first crossing (traversal order) with
// alpha > X. pos: smallest k, result in [0,257]; neg: largest k, in [-1,256].
// Seeded analytically, fixed up with the exact reference divide (ulp-robust).
__device__ __forceinline__ int seed_ptr(float X, float spv, float sr, float sd, bool pos) {
    const float kf = (X * sd + sr) / spv;
    int kk;
    if (pos) {
        kk = (int)floorf(kf) + 1;
        kk = kk < 0 ? 0 : (kk > 257 ? 257 : kk);
        while (kk > 0    && alpha_of((float)(kk-1), spv, sr, sd) >  X) --kk;
        while (kk <= 256 && alpha_of((float)kk,     spv, sr, sd) <= X) ++kk;
    } else {
        kk = (int)ceilf(kf) - 1;
        kk = kk > 256 ? 256 : (kk < -1 ? -1 : kk);
        while (kk < 256 && alpha_of((float)(kk+1), spv, sr, sd) >  X) ++kk;
        while (kk >= 0  && alpha_of((float)kk,     spv, sr, sd) <= X) --kk;
    }
    return kk;
}

// One interval: q = next crossing (incremental tM), sample voxel at midpoint,
// issue the load, advance the argmin axis by its constant alpha-delta.
#define INTERVAL(qv, stepv, voxv)                                        \
    const float qv = fminf(fminf(tM0, tM1), tM2);                        \
    const float stepv = qv - prev;                                       \
    {   const float amid = 0.5f * (prev + qv);                           \
        const float p0 = src0 + amid * sdd0;                             \
        const float p1 = src1 + amid * sdd1;                             \
        const float p2 = src2 + amid * sdd2;                             \
        float f0, f1, f2;                                                \
        if (UNIT) { f0 = p0; f1 = p1; f2 = p2; }                         \
        else      { f0 = p0 / spn0; f1 = p1 / spn1; f2 = p2 / spn2; }    \
        f0 = fminf(fmaxf(f0, 0.0f), 255.0f);                             \
        f1 = fminf(fmaxf(f1, 0.0f), 255.0f);                             \
        f2 = fminf(fmaxf(f2, 0.0f), 255.0f);                             \
        const int i0 = (int)f0, i1 = (int)f1, i2 = (int)f2;              \
        const int addr = ((((255 ^ i0) << 8) + i1) << 8) + i2;           \
        voxv = vol[addr]; }                                              \
    prev = qv;                                                           \
    {   const bool m0 = (tM0 == qv);                                     \
        const bool m1 = !m0 && (tM1 == qv);                              \
        const bool m2 = !(m0 || m1);                                     \
        tM0 = m0 ? tM0 + dl0 : tM0;                                      \
        tM1 = m1 ? tM1 + dl1 : tM1;                                      \
        tM2 = m2 ? tM2 + dl2 : tM2; }

// Count-based merge: exactly `trip` intervals (set membership decided by the
// exact pointer seeds, never by drifted comparisons). Unrolled by 2 so B's
// address math overlaps A's load latency.
template<bool UNIT>
__device__ __forceinline__ float merge_loop(
    const float* __restrict__ vol, int trip, float prev,
    float tM0, float tM1, float tM2,
    float dl0, float dl1, float dl2,
    float src0, float src1, float src2,
    float spn0, float spn1, float spn2,
    float sdd0, float sdd1, float sdd2)
{
    float acc = 0.0f;
    int n = trip;
    while (n >= 2) {
        float voxA, voxB;
        INTERVAL(qA, stepA, voxA)
        INTERVAL(qB, stepB, voxB)
        acc = fmaf(stepA, voxA, acc);
        acc = fmaf(stepB, voxB, acc);
        n -= 2;
    }
    if (n > 0) {
        float voxC;
        INTERVAL(qC, stepC, voxC)
        acc = fmaf(stepC, voxC, acc);
    }
    return acc;
}

__global__ __launch_bounds__(256)
void drr_kernel(const float* __restrict__ vol,
                const float* __restrict__ spacing,
                const float* __restrict__ sdrP,
                const float* __restrict__ thetaP,
                const float* __restrict__ phiP,
                const float* __restrict__ gammaP,
                const float* __restrict__ bxP,
                const float* __restrict__ byP,
                const float* __restrict__ bzP,
                float* __restrict__ out)
{
    const int tid = blockIdx.x * blockDim.x + threadIdx.x;
    if (tid >= NRAY * SPLIT) return;          // pad threads exit
    const int seg = tid / NRAY;               // segment in high bits
    const int rid = tid - seg * NRAY;         // lanes = consecutive rid
    const int it  = rid % HH;                 // it fastest -> coalesced i2
    const int is  = rid / HH;

    const float sdr = sdrP[0];
    const float th = thetaP[0], ph = phiP[0], ga = gammaP[0];
    const float ct = cosf(th), st = sinf(th);
    const float cp = cosf(ph), sp = sinf(ph);
    const float cg = cosf(ga), sg = sinf(ga);

    // rotation = Rz @ Ry @ Rx
    const float rot[3][3] = {
        { ct*cp, ct*sp*sg - st*cg, ct*sp*cg + st*sg },
        { st*cp, st*sp*sg + ct*cg, st*sp*cg - ct*sg },
        { -sp,   cp*sg,            cp*cg            }
    };

    float u[3], v[3], source[3], trans[3], src[3], spn[3];
    trans[0] = bxP[0]; trans[1] = byP[0]; trans[2] = bzP[0];
    for (int a = 0; a < 3; ++a) {
        source[a] = sdr * rot[a][0];
        u[a] = (sdr * rot[a][1]) / sdr;
        v[a] = (sdr * rot[a][2]) / sdr;
        src[a] = source[a] + trans[a];
        spn[a] = spacing[a];
    }

    const float tc = (float)(it - HH/2 + 1) * 2.0f;   // DELX
    const float sc = (float)(is - WW/2 + 1) * 2.0f;   // DELY

    float sdd[3];
    float nrm2 = 0.0f;
    for (int a = 0; a < 3; ++a) {
        float tg = tc * u[a] + sc * v[a];
        tg = tg - source[a];     // + center
        tg = tg + trans[a];
        float dd = (tg - src[a]) + 1e-8f;  // sdd = tgt - src + EPS
        sdd[a] = dd;
        nrm2 = nrm2 + dd * dd;
    }
    const bool unit = (spn[0] == 1.0f) & (spn[1] == 1.0f) & (spn[2] == 1.0f);

    float amin = -INFINITY, amax = INFINITY;
    for (int a = 0; a < 3; ++a) {
        float a0 = (0.0f - src[a]) / sdd[a];
        float a1 = (256.0f * spn[a] - src[a]) / sdd[a];
        amin = fmaxf(amin, fminf(a0, a1));
        amax = fminf(amax, fmaxf(a0, a1));
    }

    float acc = 0.0f;
    if (amax > amin) {
        // Segment window (blo, bhi]; identical boundary arithmetic in all segs
        // of a ray, so the windows partition (amin, amax] exactly.
        const float blo = (seg == 0) ? amin
                        : amin + (amax - amin) * ((float)seg / (float)SPLIT);
        const float bhi = (seg == SPLIT - 1) ? amax
                        : amin + (amax - amin) * ((float)(seg + 1) / (float)SPLIT);

        float tM[3], dl[3];
        float prev = -INFINITY;   // largest in-range alpha <= blo
        int trip = 0;

        for (int a = 0; a < 3; ++a) {
            const float sd = sdd[a], sr = src[a], spv = spn[a];
            const bool pos = sd > 0.0f;
            const int ks = seed_ptr(blo, spv, sr, sd, pos);
            const int ke = seed_ptr(bhi, spv, sr, sd, pos);
            int cnt;
            if (pos) {
                cnt = ke - ks;
                if (ks - 1 >= 0) {
                    const float ap = alpha_of((float)(ks-1), spv, sr, sd);
                    if (ap >= amin && ap > prev) prev = ap;
                }
                tM[a] = (ks <= 256) ? alpha_of((float)ks, spv, sr, sd) : INFINITY;
            } else {
                cnt = ks - ke;
                if (ks + 1 <= 256) {
                    const float ap = alpha_of((float)(ks+1), spv, sr, sd);
                    if (ap >= amin && ap > prev) prev = ap;
                }
                tM[a] = (ks >= 0) ? alpha_of((float)ks, spv, sr, sd) : INFINITY;
            }
            if (cnt < 0) cnt = 0;
            trip += cnt;
            dl[a] = fabsf(spv / sd);   // constant alpha increment per crossing
        }

        if (unit) {
            acc = merge_loop<true >(vol, trip, prev,
                                    tM[0], tM[1], tM[2], dl[0], dl[1], dl[2],
                                    src[0], src[1], src[2],
                                    spn[0], spn[1], spn[2],
                                    sdd[0], sdd[1], sdd[2]);
        } else {
            acc = merge_loop<false>(vol, trip, prev,
                                    tM[0], tM[1], tM[2], dl[0], dl[1], dl[2],
                                    src[0], src[1], src[2],
                                    spn[0], spn[1], spn[2],
                                    sdd[0], sdd[1], sdd[2]);
        }
    }

    atomicAdd(&out[it * WW + is], acc * sqrtf(nrm2));
}

extern "C" void kernel_launch(void* const* d_in, const int* in_sizes, int n_in,
                              void* d_out, int out_size, void* d_ws, size_t ws_size,
                              hipStream_t stream)
{
    const float* vol     = (const float*)d_in[0];
    const float* spacing = (const float*)d_in[1];
    const float* sdr     = (const float*)d_in[2];
    const float* theta   = (const float*)d_in[3];
    const float* phi     = (const float*)d_in[4];
    const float* gamma   = (const float*)d_in[5];
    const float* bx      = (const float*)d_in[6];
    const float* by      = (const float*)d_in[7];
    const float* bz      = (const float*)d_in[8];
    float* out = (float*)d_out;

    // re-zero the output every replay (graph captures this memset node);
    // required because partial sums are atomically accumulated.
    hipMemsetAsync(out, 0, (size_t)out_size * sizeof(float), stream);

    // SPLIT=13: 520000 threads ~= 8125 waves ~= one residency round.
    const int threads = NRAY * SPLIT;
    const int block   = 256;
    const int grid    = (threads + block - 1) / block;   // 2032
    drr_kernel<<<grid, block, 0, stream>>>(vol, spacing, sdr, theta, phi, gamma,
                                           bx, by, bz, out);
}

// Round 9
// 55.889 us; speedup vs baseline: 1.6008x; 1.0242x over previous
//
#include <hip/hip_runtime.h>
#include <math.h>

// Keep non-contracted float math in all expressions that feed discrete
// decisions (alpha seeds, voxel trunc) — matches numpy/JAX op-for-op.
#pragma clang fp contract(off)

#define SPLIT 13
#define BATCH 8
static constexpr int HH = 200, WW = 200;
static constexpr int NRAY = HH * WW;

__device__ __forceinline__ float alpha_of(float k, float sp, float src, float sdd) {
    return (k * sp - src) / sdd;   // reference: (k*spacing - src)/sdd, mul-sub-div
}

// Traversal pointer at threshold X: first crossing (traversal order) with
// alpha > X. pos: smallest k, result in [0,257]; neg: largest k, in [-1,256].
// Seeded analytically, fixed up with the exact reference divide (ulp-robust).
__device__ __forceinline__ int seed_ptr(float X, float spv, float sr, float sd, bool pos) {
    const float kf = (X * sd + sr) / spv;
    int kk;
    if (pos) {
        kk = (int)floorf(kf) + 1;
        kk = kk < 0 ? 0 : (kk > 257 ? 257 : kk);
        while (kk > 0    && alpha_of((float)(kk-1), spv, sr, sd) >  X) --kk;
        while (kk <= 256 && alpha_of((float)kk,     spv, sr, sd) <= X) ++kk;
    } else {
        kk = (int)ceilf(kf) - 1;
        kk = kk > 256 ? 256 : (kk < -1 ? -1 : kk);
        while (kk < 256 && alpha_of((float)(kk+1), spv, sr, sd) >  X) ++kk;
        while (kk >= 0  && alpha_of((float)kk,     spv, sr, sd) <= X) --kk;
    }
    return kk;
}

// Generate one interval's (step, addr) from the tM recurrence and advance.
// Identical float ops to the round-8 passing kernel (bit-identical stream).
#define GEN_INTERVAL(stepv, addrv)                                       \
    {   const float q = fminf(fminf(tM0, tM1), tM2);                     \
        stepv = q - prev;                                                \
        const float amid = 0.5f * (prev + q);                            \
        const float p0 = src0 + amid * sdd0;                             \
        const float p1 = src1 + amid * sdd1;                             \
        const float p2 = src2 + amid * sdd2;                             \
        float f0, f1, f2;                                                \
        if (UNIT) { f0 = p0; f1 = p1; f2 = p2; }                         \
        else      { f0 = p0 / spn0; f1 = p1 / spn1; f2 = p2 / spn2; }    \
        f0 = fminf(fmaxf(f0, 0.0f), 255.0f);                             \
        f1 = fminf(fmaxf(f1, 0.0f), 255.0f);                             \
        f2 = fminf(fmaxf(f2, 0.0f), 255.0f);                             \
        const int i0 = (int)f0, i1 = (int)f1, i2 = (int)f2;              \
        addrv = ((((255 ^ i0) << 8) + i1) << 8) + i2;                    \
        prev = q;                                                        \
        const bool m0 = (tM0 == q);                                      \
        const bool m1 = !m0 && (tM1 == q);                               \
        const bool m2 = !(m0 || m1);                                     \
        tM0 = m0 ? tM0 + dl0 : tM0;                                      \
        tM1 = m1 ? tM1 + dl1 : tM1;                                      \
        tM2 = m2 ? tM2 + dl2 : tM2; }

// Count-based merge, batch-8 pipelined: 8 addresses generated by the cheap
// recurrence, 8 independent loads in flight, then 8 fmafs in interval order
// (accumulation order identical to the unbatched loop).
template<bool UNIT>
__device__ __forceinline__ float merge_loop(
    const float* __restrict__ vol, int trip, float prev,
    float tM0, float tM1, float tM2,
    float dl0, float dl1, float dl2,
    float src0, float src1, float src2,
    float spn0, float spn1, float spn2,
    float sdd0, float sdd1, float sdd2)
{
    float acc = 0.0f;
    int n = trip;
    while (n >= BATCH) {
        float stepv[BATCH], vox[BATCH];
        int addr[BATCH];
        #pragma unroll
        for (int i = 0; i < BATCH; ++i) {
            GEN_INTERVAL(stepv[i], addr[i])
            vox[i] = vol[addr[i]];           // issue load; consumed below
        }
        #pragma unroll
        for (int i = 0; i < BATCH; ++i)
            acc = fmaf(stepv[i], vox[i], acc);
        n -= BATCH;
    }
    while (n > 0) {
        float stepv, vox;
        int addr;
        GEN_INTERVAL(stepv, addr)
        vox = vol[addr];
        acc = fmaf(stepv, vox, acc);
        --n;
    }
    return acc;
}

__global__ __launch_bounds__(256)
void drr_kernel(const float* __restrict__ vol,
                const float* __restrict__ spacing,
                const float* __restrict__ sdrP,
                const float* __restrict__ thetaP,
                const float* __restrict__ phiP,
                const float* __restrict__ gammaP,
                const float* __restrict__ bxP,
                const float* __restrict__ byP,
                const float* __restrict__ bzP,
                float* __restrict__ out)
{
    const int tid = blockIdx.x * blockDim.x + threadIdx.x;
    if (tid >= NRAY * SPLIT) return;          // pad threads exit
    const int seg = tid / NRAY;               // segment in high bits
    const int rid = tid - seg * NRAY;         // lanes = consecutive rid
    const int it  = rid % HH;                 // it fastest -> coalesced i2
    const int is  = rid / HH;

    const float sdr = sdrP[0];
    const float th = thetaP[0], ph = phiP[0], ga = gammaP[0];
    const float ct = cosf(th), st = sinf(th);
    const float cp = cosf(ph), sp = sinf(ph);
    const float cg = cosf(ga), sg = sinf(ga);

    // rotation = Rz @ Ry @ Rx
    const float rot[3][3] = {
        { ct*cp, ct*sp*sg - st*cg, ct*sp*cg + st*sg },
        { st*cp, st*sp*sg + ct*cg, st*sp*cg - ct*sg },
        { -sp,   cp*sg,            cp*cg            }
    };

    float u[3], v[3], source[3], trans[3], src[3], spn[3];
    trans[0] = bxP[0]; trans[1] = byP[0]; trans[2] = bzP[0];
    for (int a = 0; a < 3; ++a) {
        source[a] = sdr * rot[a][0];
        u[a] = (sdr * rot[a][1]) / sdr;
        v[a] = (sdr * rot[a][2]) / sdr;
        src[a] = source[a] + trans[a];
        spn[a] = spacing[a];
    }

    const float tc = (float)(it - HH/2 + 1) * 2.0f;   // DELX
    const float sc = (float)(is - WW/2 + 1) * 2.0f;   // DELY

    float sdd[3];
    float nrm2 = 0.0f;
    for (int a = 0; a < 3; ++a) {
        float tg = tc * u[a] + sc * v[a];
        tg = tg - source[a];     // + center
        tg = tg + trans[a];
        float dd = (tg - src[a]) + 1e-8f;  // sdd = tgt - src + EPS
        sdd[a] = dd;
        nrm2 = nrm2 + dd * dd;
    }
    const bool unit = (spn[0] == 1.0f) & (spn[1] == 1.0f) & (spn[2] == 1.0f);

    float amin = -INFINITY, amax = INFINITY;
    for (int a = 0; a < 3; ++a) {
        float a0 = (0.0f - src[a]) / sdd[a];
        float a1 = (256.0f * spn[a] - src[a]) / sdd[a];
        amin = fmaxf(amin, fminf(a0, a1));
        amax = fminf(amax, fmaxf(a0, a1));
    }

    float acc = 0.0f;
    if (amax > amin) {
        // Segment window (blo, bhi]; identical boundary arithmetic in all segs
        // of a ray, so the windows partition (amin, amax] exactly.
        const float blo = (seg == 0) ? amin
                        : amin + (amax - amin) * ((float)seg / (float)SPLIT);
        const float bhi = (seg == SPLIT - 1) ? amax
                        : amin + (amax - amin) * ((float)(seg + 1) / (float)SPLIT);

        float tM[3], dl[3];
        float prev = -INFINITY;   // largest in-range alpha <= blo
        int trip = 0;

        for (int a = 0; a < 3; ++a) {
            const float sd = sdd[a], sr = src[a], spv = spn[a];
            const bool pos = sd > 0.0f;
            const int ks = seed_ptr(blo, spv, sr, sd, pos);
            const int ke = seed_ptr(bhi, spv, sr, sd, pos);
            int cnt;
            if (pos) {
                cnt = ke - ks;
                if (ks - 1 >= 0) {
                    const float ap = alpha_of((float)(ks-1), spv, sr, sd);
                    if (ap >= amin && ap > prev) prev = ap;
                }
                tM[a] = (ks <= 256) ? alpha_of((float)ks, spv, sr, sd) : INFINITY;
            } else {
                cnt = ks - ke;
                if (ks + 1 <= 256) {
                    const float ap = alpha_of((float)(ks+1), spv, sr, sd);
                    if (ap >= amin && ap > prev) prev = ap;
                }
                tM[a] = (ks >= 0) ? alpha_of((float)ks, spv, sr, sd) : INFINITY;
            }
            if (cnt < 0) cnt = 0;
            trip += cnt;
            dl[a] = fabsf(spv / sd);   // constant alpha increment per crossing
        }

        if (unit) {
            acc = merge_loop<true >(vol, trip, prev,
                                    tM[0], tM[1], tM[2], dl[0], dl[1], dl[2],
                                    src[0], src[1], src[2],
                                    spn[0], spn[1], spn[2],
                                    sdd[0], sdd[1], sdd[2]);
        } else {
            acc = merge_loop<false>(vol, trip, prev,
                                    tM[0], tM[1], tM[2], dl[0], dl[1], dl[2],
                                    src[0], src[1], src[2],
                                    spn[0], spn[1], spn[2],
                                    sdd[0], sdd[1], sdd[2]);
        }
    }

    atomicAdd(&out[it * WW + is], acc * sqrtf(nrm2));
}

extern "C" void kernel_launch(void* const* d_in, const int* in_sizes, int n_in,
                              void* d_out, int out_size, void* d_ws, size_t ws_size,
                              hipStream_t stream)
{
    const float* vol     = (const float*)d_in[0];
    const float* spacing = (const float*)d_in[1];
    const float* sdr     = (const float*)d_in[2];
    const float* theta   = (const float*)d_in[3];
    const float* phi     = (const float*)d_in[4];
    const float* gamma   = (const float*)d_in[5];
    const float* bx      = (const float*)d_in[6];
    const float* by      = (const float*)d_in[7];
    const float* bz      = (const float*)d_in[8];
    float* out = (float*)d_out;

    // re-zero the output every replay (graph captures this memset node);
    // required because partial sums are atomically accumulated.
    hipMemsetAsync(out, 0, (size_t)out_size * sizeof(float), stream);

    // SPLIT=13: 520000 threads ~= 8125 waves ~= one residency round.
    const int threads = NRAY * SPLIT;
    const int block   = 256;
    const int grid    = (threads + block - 1) / block;   // 2032
    drr_kernel<<<grid, block, 0, stream>>>(vol, spacing, sdr, theta, phi, gamma,
                                           bx, by, bz, out);
}